// Round 10
// baseline (219.792 us; speedup 1.0000x reference)
//
#include <hip/hip_runtime.h>

#define BB 8
#define LL 1024
#define DD 768
#define HH 12
#define HD 64

typedef short s16x8 __attribute__((ext_vector_type(8)));
typedef float f32x4 __attribute__((ext_vector_type(4)));
typedef unsigned int u32x4 __attribute__((ext_vector_type(4)));

static __device__ __forceinline__ unsigned short f2bf(float f){
  unsigned int u = __builtin_bit_cast(unsigned int, f);
  u = (u + 0x7FFFu + ((u >> 16) & 1u)) >> 16;
  return (unsigned short)u;
}

// packed f32x2 -> bf16x2 via hardware cvt_pk (1 VALU); low 16 = a
static __device__ __forceinline__ unsigned int cvtpk_bf(float a, float b){
  unsigned int r;
  asm("v_cvt_pk_bf16_f32 %0, %1, %2" : "=v"(r) : "v"(a), "v"(b));
  return r;
}

// cross-lane swaps (gfx950): swap32: a[32:63] <-> b[0:31];
// swap16 (per 32-lane half): a[16:31] <-> b[0:15], a[48:63] <-> b[32:47]
static __device__ __forceinline__ void swap32(unsigned int& a, unsigned int& b){
  asm("v_permlane32_swap_b32 %0, %1" : "+v"(a), "+v"(b));
}
static __device__ __forceinline__ void swap16(unsigned int& a, unsigned int& b){
  asm("v_permlane16_swap_b32 %0, %1" : "+v"(a), "+v"(b));
}

// hardware exp2: 1 instr, no OCML denormal fixup (inputs <= ~0 here; FTZ ok)
static __device__ __forceinline__ float hexp2(float x){
#if __has_builtin(__builtin_amdgcn_exp2f)
  return __builtin_amdgcn_exp2f(x);
#else
  return exp2f(x);
#endif
}

static __device__ __forceinline__ f32x4 mfma16(s16x8 a, s16x8 b, f32x4 c){
  return __builtin_amdgcn_mfma_f32_16x16x32_bf16(a, b, c, 0, 0, 0);
}

// async global->LDS, 16B per lane; LDS dest is wave-uniform base + lane*16
static __device__ __forceinline__ void gld_lds16(const void* g, void* l){
  __builtin_amdgcn_global_load_lds(
      (const __attribute__((address_space(1))) void*)g,
      (__attribute__((address_space(3))) void*)l, 16, 0, 0);
}

// ------------- merged prep+rmsnorm: one launch (R8, proven) -----------------
__global__ __launch_bounds__(256) void prep_norm_kernel(const float* __restrict__ x,
                                                        const float* __restrict__ wn,
                                                        unsigned short* __restrict__ xn,
                                                        const float* __restrict__ w_in,
                                                        unsigned short* __restrict__ winb,
                                                        const float* __restrict__ w_out,
                                                        unsigned short* __restrict__ woutb,
                                                        const float* __restrict__ bp,
                                                        float* __restrict__ table){
  __shared__ float red[4];
  int bid = blockIdx.x, t = threadIdx.x;
  if (bid < 8192){                                  // ---- RMSNorm -> bf16 ----
    int row = bid;
    const float* xr = x + (size_t)row*DD;
    float v0 = xr[t], v1 = xr[t+256], v2 = xr[t+512];
    float ss = v0*v0 + v1*v1 + v2*v2;
    #pragma unroll
    for (int m = 1; m < 64; m <<= 1) ss += __shfl_xor(ss, m, 64);
    if ((t & 63) == 0) red[t >> 6] = ss;
    __syncthreads();
    float tot = red[0] + red[1] + red[2] + red[3];
    float sc = rsqrtf(tot*(1.0f/DD) + 1e-5f);
    unsigned short* xo = xn + (size_t)row*DD;
    xo[t]     = f2bf(v0*sc*wn[t]);
    xo[t+256] = f2bf(v1*sc*wn[t+256]);
    xo[t+512] = f2bf(v2*sc*wn[t+512]);
  } else if (bid < 8192 + 1728){                    // ---- w_in cvt ----
    int i = (bid - 8192)*256 + t;
    float4 v = ((const float4*)w_in)[i];
    ushort4 o;
    o.x = f2bf(v.x); o.y = f2bf(v.y); o.z = f2bf(v.z); o.w = f2bf(v.w);
    ((ushort4*)winb)[i] = o;
  } else if (bid < 8192 + 2304){                    // ---- w_out cvt ----
    int i = (bid - 8192 - 1728)*256 + t;
    float4 v = ((const float4*)w_out)[i];
    ushort4 o;
    o.x = f2bf(v.x); o.y = f2bf(v.y); o.z = f2bf(v.z); o.w = f2bf(v.w);
    ((ushort4*)woutb)[i] = o;
  } else {                                          // ---- bias table ----
    int idx = (bid - 8192 - 2304)*256 + t;
    if (idx >= HH*3969) return;
    int hh = idx/3969, rem = idx - hh*3969;
    int dy = rem/63 - 31, dx = rem%63 - 31;
    float o  = bp[hh*6+0], c = bp[hh*6+1], w = bp[hh*6+2];
    float p  = bp[hh*6+3], dl = bp[hh*6+4], m = bp[hh*6+5];
    float theta = atan2f((float)dx, (float)dy);     // arctan2(dist1, dist0)
    float r = sqrtf((float)(dy*dy + dx*dx) + 1e-12f);
    float t1 = powf(fmaxf(r - o, 0.0f), fabsf(c));
    float co = cosf((theta - p)*w*0.5f);
    float t2 = 1.0f - fabsf(tanhf(dl))*powf(co*co, fabsf(m));
    table[idx] = t1*t2*1.44269504f;                 // * log2(e)
  }
}

// ---------------- bmax[h][qy][qx] = max over the 32x32 table subwindow --------------
__global__ __launch_bounds__(64) void bmax_kernel(const float* __restrict__ table,
                                                  float* __restrict__ bmax){
  int qy = blockIdx.x, h = blockIdx.y;
  __shared__ float m1[63];
  int t = threadIdx.x;
  const float* tb = table + h*3969;
  if (t < 63){
    float m = -3.0e38f;
    #pragma unroll 4
    for (int row = qy; row < qy + 32; row++) m = fmaxf(m, tb[row*63 + t]);
    m1[t] = m;
  }
  __syncthreads();
  if (t < 32){
    float m = -3.0e38f;
    #pragma unroll 4
    for (int c = t; c < t + 32; c++) m = fmaxf(m, m1[c]);
    bmax[(h*32 + qy)*32 + t] = m;
  }
}

// ---------------- GEMM, 3-stage pipeline, counted vmcnt, LDS chunk-swizzle --------
// C[M,N] = A[M,K] @ B[N,K]^T + bias[N].  Tile 128 x TN, 4 waves 2x2.
// R10: Q-region columns (bn<768, whole blocks since TN=128 | 768) are scaled
// by log2e/8 = 0.18033688 at the Ct fill (bias scaled with them) -> attn's QK
// MFMA output is already in exp2 domain, removing the per-element fma there.
template<int MODE, int TN, typename OutT>
__global__ __launch_bounds__(256) void gemm_bt_kernel(const unsigned short* __restrict__ A,
                                                      const unsigned short* __restrict__ B,
                                                      const float* __restrict__ bias,
                                                      OutT* __restrict__ C,
                                                      unsigned short* __restrict__ qp,
                                                      unsigned short* __restrict__ kp,
                                                      unsigned short* __restrict__ vt2,
                                                      int M, int N, int K){
  constexpr int NT = TN/32;                 // nt tiles per wave (TN=128 -> 4, TN=64 -> 2)
  constexpr int SMEM_BYTES = 192*(128 + TN);  // 3 A-buffers + 3 B-buffers
  __shared__ __align__(16) char smem[SMEM_BYTES];
  unsigned short* As = (unsigned short*)smem;                  // [3][4096]
  unsigned short* Bs = (unsigned short*)(smem + 3*128*32*2);   // [3][TN*32]
  int tid = threadIdx.x;
  int w = tid >> 6, lane = tid & 63, quad = lane >> 4, col = lane & 15;
  int wm = (w >> 1)*64, wn = (w & 1)*(TN/2);
  int bm = blockIdx.x*128, bn = blockIdx.y*TN;

  int srow = lane >> 2;
  int schunk = (((lane & 3) ^ ((lane >> 3) & 3)))*8;   // swizzled source chunk
  const unsigned short* ga0 = A + (size_t)(bm + w*32 + srow)*K + schunk;
  const unsigned short* ga1 = ga0 + (size_t)16*K;
  const unsigned short* gb0 = B + (size_t)(bn + w*(TN/4) + srow)*K + schunk;
  const unsigned short* gb1 = gb0 + (size_t)16*K;     // only used when TN==128

  auto stage = [&](int t, int bi){
    int kk = t*32;
    gld_lds16(ga0 + kk, As + bi*4096 + (w*32)*32);
    gld_lds16(ga1 + kk, As + bi*4096 + (w*32 + 16)*32);
    gld_lds16(gb0 + kk, Bs + bi*(TN*32) + (w*(TN/4))*32);
    if (TN == 128) gld_lds16(gb1 + kk, Bs + bi*(TN*32) + (w*32 + 16)*32);
  };

  f32x4 acc[4][NT];
  #pragma unroll
  for (int mt = 0; mt < 4; mt++)
    #pragma unroll
    for (int nt = 0; nt < NT; nt++) acc[mt][nt] = (f32x4){0.f,0.f,0.f,0.f};

  // prologue: stage tiles 0 and 1 (2-deep in flight)
  stage(0, 0);
  stage(1, 1);

  int rsw = (col >> 1) & 3;                 // swizzled read chunk = quad ^ rsw
  int rchunk = (quad ^ rsw)*8;

  int KT = K >> 5;
  int buf = 0, nbuf = 2;
  for (int t = 0; t < KT; t++){
    // counted wait BEFORE barrier: own L(t) landed (FIFO vmcnt), newer L(t+1)
    // loads may remain in flight. Barrier then publishes all waves' L(t).
    if (t < KT - 1){
      if (TN == 128) asm volatile("s_waitcnt vmcnt(4)" ::: "memory");
      else           asm volatile("s_waitcnt vmcnt(3)" ::: "memory");
    } else {
      asm volatile("s_waitcnt vmcnt(0)" ::: "memory");
    }
    __builtin_amdgcn_s_barrier();
    asm volatile("" ::: "memory");          // pin LDS reads below the barrier
    if (t + 2 < KT) stage(t + 2, nbuf);
    s16x8 af[4], bfr[NT];
    #pragma unroll
    for (int mt = 0; mt < 4; mt++)
      af[mt] = *(const s16x8*)&As[buf*4096 + (wm + mt*16 + col)*32 + rchunk];
    #pragma unroll
    for (int nt = 0; nt < NT; nt++)
      bfr[nt] = *(const s16x8*)&Bs[buf*(TN*32) + (wn + nt*16 + col)*32 + rchunk];
    #pragma unroll
    for (int mt = 0; mt < 4; mt++)
      #pragma unroll
      for (int nt = 0; nt < NT; nt++)
        acc[mt][nt] = mfma16(af[mt], bfr[nt], acc[mt][nt]);
    buf  = (buf  == 2) ? 0 : buf  + 1;
    nbuf = (nbuf == 2) ? 0 : nbuf + 1;
  }

  if (MODE == 1){
    __syncthreads();                       // all waves done reading As/Bs
    unsigned short* Ct = (unsigned short*)smem;
    if (bn >= 1536){
      // ---- V blocks: fill TRANSPOSED (Ct[col][row]), store in vt2 layout ----
      #pragma unroll
      for (int mt = 0; mt < 4; mt++)
        #pragma unroll
        for (int nt = 0; nt < NT; nt++){
          int cc = wn + nt*16 + col;
          float bv = bias[bn + cc];
          #pragma unroll
          for (int r = 0; r < 4; r++){
            int row = wm + mt*16 + quad*4 + r;
            Ct[cc*136 + row] = f2bf(acc[mt][nt][r] + bv);
          }
        }
      __syncthreads();
      int bb = bm >> 10;
      #pragma unroll
      for (int e = 0; e < 8; e++){
        int id = e*256 + tid;              // 2048 chunks = 128 d-cols x 16 row-chunks
        int dcol = id >> 4, rowch = id & 15;
        s16x8 val = *(const s16x8*)&Ct[dcol*136 + rowch*8];
        int cl = bn + dcol - 1536;
        int h = cl >> 6, d = cl & 63;
        int l = bm + rowch*8;
        size_t base = ((size_t)(bb*HH + h))*65536 + (size_t)((l >> 5) & 31)*2048;
        *(s16x8*)(vt2 + base + d*32 + (l & 31)) = val;
      }
    } else {
      // ---- Q/K blocks: row-major staging, 16B coalesced stores (proven) ----
      // R10: Q columns (bn<768) pre-scaled by log2e/8 (bias included).
      float qsc = (bn < 768) ? 0.18033688f : 1.0f;
      #pragma unroll
      for (int mt = 0; mt < 4; mt++)
        #pragma unroll
        for (int nt = 0; nt < NT; nt++){
          int cc = wn + nt*16 + col;
          float bv = bias[bn + cc];
          #pragma unroll
          for (int r = 0; r < 4; r++){
            int row = wm + mt*16 + quad*4 + r;
            Ct[row*136 + cc] = f2bf((acc[mt][nt][r] + bv)*qsc);
          }
        }
      __syncthreads();
      #pragma unroll
      for (int e = 0; e < 8; e++){
        int id = e*256 + tid;              // 2048 chunks = 128 rows x 16 chunks
        int row = id >> 4, ch = id & 15;
        s16x8 val = *(const s16x8*)&Ct[row*136 + ch*8];
        int rw = bm + row;
        int cl0 = bn + ch*8;
        int part = cl0 >= 768 ? 1 : 0;
        int hd = cl0 - part*768;
        int hh2 = hd >> 6, d0 = hd & 63;
        int bb = rw >> 10, l = rw & 1023;
        size_t base = (((size_t)bb*HH + hh2)*LL + l)*64;
        if (part == 0) *(s16x8*)(qp + base + d0) = val;
        else           *(s16x8*)(kp + base + (((d0>>3) ^ (l&7)) << 3)) = val;
      }
    }
  } else {
    // ---- LDS-staged coalesced f32 epilogue (float4 stores), proven R7 ----
    __syncthreads();
    float* Cf = (float*)smem;              // [128][68] f32, rows 16B-aligned (272B)
    #pragma unroll
    for (int mt = 0; mt < 4; mt++)
      #pragma unroll
      for (int nt = 0; nt < NT; nt++){
        int cc = wn + nt*16 + col;
        float bv = bias[bn + cc];
        #pragma unroll
        for (int r = 0; r < 4; r++){
          int row = wm + mt*16 + quad*4 + r;
          Cf[row*68 + cc] = acc[mt][nt][r] + bv;
        }
      }
    __syncthreads();
    #pragma unroll
    for (int e = 0; e < 8; e++){
      int id = e*256 + tid;                // 2048 chunks = 128 rows x 16 float4
      int row = id >> 4, ch = id & 15;
      float4 val = *(const float4*)&Cf[row*68 + ch*4];
      *(float4*)&C[(size_t)(bm + row)*N + bn + ch*4] = val;
    }
  }
}

// ---------------- fused attention: barrier-free, 2-wave blocks ----------------
// R10 chain-shortening: Q carries the log2e/8 scale (GEMM epilogue), and the
// bias enters as the QK MFMA ACCUMULATOR INIT {tl[base-r] - mh} (identical
// r-mapping to the old post-MFMA fma, by construction). The 8 tlv values per
// g are prefetched 2 steps ahead (A/B, like K/V), so the LDS load + subtract
// sit off the critical chain. New tail: MFMA -> exp2 -> cvt_pk -> permlane
// -> PV MFMA. No setprio (R7 null), no K-split (R8 regression).
__global__ __launch_bounds__(128) void attn_kernel(const unsigned short* __restrict__ qp,
                                                   const unsigned short* __restrict__ kp,
                                                   const unsigned short* __restrict__ vt2,
                                                   const float* __restrict__ table,
                                                   const float* __restrict__ bmax,
                                                   const float* __restrict__ pos,
                                                   unsigned short* __restrict__ o_out){
  int i = blockIdx.x;                     // i = (bhhi<<7)|(wp<<6)|(qt<<3)|bhlow
  int bh = (i >> 7)*8 + (i & 7);          // i%8 == bh%8 (XCD-local K/V)
  int qt = (i >> 3) & 7;
  int wp = (i >> 6) & 1;                  // which wave-pair of the 128-row tile
  int b = bh/HH, h = bh - b*HH;
  int tid = threadIdx.x, w = tid >> 6, lane = tid & 63, quad = lane >> 4, col = lane & 15;
  __shared__ float tl[3969];

  const unsigned short* kgp = kp  + (size_t)bh*65536;
  const unsigned short* vgp = vt2 + (size_t)bh*65536;

  // per-lane fragment offsets (in shorts):
  // K: row=key=col (stride 64), chunk c at position c^(col&7) (GEMM swizzle)
  // V: row=d=col (stride 32), j-chunk = quad
  int sw = col & 7;
  int k_r0 = col*64 + ((quad ^ sw) << 3);          // keys 0-15,  d = quad*8
  int k_r1 = col*64 + (((quad + 4) ^ sw) << 3);    // keys 0-15,  d = 32+quad*8
  int v_r  = col*32 + quad*8;                      // d = col,    j = quad*8

  s16x8 kA[4], vA[4], kB[4], vB[4];
  auto issue = [&](int t, s16x8 (&k)[4], s16x8 (&v)[4]){
    const unsigned short* kt = kgp + t*2048;
    const unsigned short* vt = vgp + t*2048;
    k[0] = *(const s16x8*)(kt + k_r0);
    k[1] = *(const s16x8*)(kt + k_r1);
    k[2] = *(const s16x8*)(kt + 1024 + k_r0);      // keys 16-31
    k[3] = *(const s16x8*)(kt + 1024 + k_r1);
    v[0] = *(const s16x8*)(vt + v_r);
    v[1] = *(const s16x8*)(vt + v_r + 512);
    v[2] = *(const s16x8*)(vt + v_r + 1024);
    v[3] = *(const s16x8*)(vt + v_r + 1536);
  };
  issue(0, kA, vA);                 // overlap with tl staging
  issue(1, kB, vB);

  for (int j = tid; j < 3969; j += 128) tl[j] = table[h*3969 + j];
  const float* pb = pos + (size_t)b*2048;

  int qw = qt*128 + (wp*2 + w)*32;  // same q coverage as R3's 4-wave block
  const unsigned short* qpb = qp + (size_t)bh*65536;
  s16x8 qa[2][2];
  int cq[2];
  float mh[2];
  #pragma unroll
  for (int g = 0; g < 2; g++){
    int q = qw + g*16 + col;
    size_t qo = (size_t)q*64 + quad*8;
    qa[g][0] = *(const s16x8*)(qpb + qo);
    qa[g][1] = *(const s16x8*)(qpb + qo + 32);
    int qy = __float2int_rn(pb[q*2]);
    int qx = __float2int_rn(pb[q*2 + 1]);
    cq[g] = qy*63 + qx + 1984 - quad*4;
    mh[g] = bmax[(h*32 + qy)*32 + qx];    // exp2-domain window max
  }

  s16x8 ones;                               // bf16 1.0 row for the l-sum MFMA
  #pragma unroll
  for (int e = 0; e < 8; e++) ones[e] = (short)0x3F80;

  f32x4 o[2][4];
  f32x4 l_acc[2];
  #pragma unroll
  for (int g = 0; g < 2; g++){
    #pragma unroll
    for (int nt = 0; nt < 4; nt++) o[g][nt] = (f32x4){0.f,0.f,0.f,0.f};
    l_acc[g] = (f32x4){0.f,0.f,0.f,0.f};
  }

  __syncthreads();                          // tl visible (only barrier in kernel)

  // tlv prefetch: acc-init values {tl[base-r]-mh} for lo (r 0..3) and hi
  // (base-16-r), per g. Loaded from LDS + subtracted OFF the critical chain.
  f32x4 tA[2][2], tB[2][2];                 // [g][lo/hi]
  auto tlfetch = [&](int t, f32x4 (&tv)[2][2]){
    int kyt = 63*t;
    #pragma unroll
    for (int g = 0; g < 2; g++){
      int base = cq[g] - kyt;
      #pragma unroll
      for (int r = 0; r < 4; r++){
        tv[g][0][r] = tl[base - r]      - mh[g];
        tv[g][1][r] = tl[base - r - 16] - mh[g];
      }
    }
  };
  tlfetch(0, tA);
  tlfetch(1, tB);

  auto step = [&](s16x8 (&k)[4], s16x8 (&v)[4], f32x4 (&tv)[2][2]){
    #pragma unroll
    for (int g = 0; g < 2; g++){
      f32x4 s_lo = mfma16(k[0], qa[g][0], tv[g][0]);  s_lo = mfma16(k[1], qa[g][1], s_lo);
      f32x4 s_hi = mfma16(k[2], qa[g][0], tv[g][1]);  s_hi = mfma16(k[3], qa[g][1], s_hi);
      float pl[4], ph[4];
      #pragma unroll
      for (int r = 0; r < 4; r++){
        pl[r] = hexp2(s_lo[r]);             // Q pre-scaled; bias in acc init
        ph[r] = hexp2(s_hi[r]);
      }
      // lane holds P for keys {4q..4q+3} (pl) and {16+4q..16+4q+3} (ph), q=quad.
      // cvt_pk + 4 permlane swaps deliver the PV B-fragment to every quad.
      unsigned int wA = cvtpk_bf(pl[0], pl[1]);
      unsigned int wB = cvtpk_bf(pl[2], pl[3]);
      unsigned int wC = cvtpk_bf(ph[0], ph[1]);
      unsigned int wD = cvtpk_bf(ph[2], ph[3]);
      swap32(wA, wC);  swap32(wB, wD);
      swap16(wA, wC);  swap16(wB, wD);
      u32x4 pv4; pv4.x = wA; pv4.y = wB; pv4.z = wC; pv4.w = wD;
      s16x8 pf = __builtin_bit_cast(s16x8, pv4);
      l_acc[g] = mfma16(ones, pf, l_acc[g]);    // denominator on the MFMA pipe
      o[g][0] = mfma16(v[0], pf, o[g][0]);
      o[g][1] = mfma16(v[1], pf, o[g][1]);
      o[g][2] = mfma16(v[2], pf, o[g][2]);
      o[g][3] = mfma16(v[3], pf, o[g][3]);
    }
  };

  for (int t = 0; t < 32; t += 2){
    step(kA, vA, tA);
    if (t + 2 < 32){ issue(t + 2, kA, vA); tlfetch(t + 2, tA); }
    step(kB, vB, tB);
    if (t + 3 < 32){ issue(t + 3, kB, vB); tlfetch(t + 3, tB); }
  }

  #pragma unroll
  for (int g = 0; g < 2; g++){
    float inv = 1.0f / l_acc[g][0];           // full sum already in every lane
    int q = qw + g*16 + col;
    unsigned short* orow = o_out + (size_t)(b*LL + q)*DD + h*64;
    #pragma unroll
    for (int nt = 0; nt < 4; nt++){
      uint2 pkd;
      pkd.x = cvtpk_bf(o[g][nt][0]*inv, o[g][nt][1]*inv);
      pkd.y = cvtpk_bf(o[g][nt][2]*inv, o[g][nt][3]*inv);
      *(uint2*)&orow[nt*16 + quad*4] = pkd;
    }
  }
}

extern "C" void kernel_launch(void* const* d_in, const int* in_sizes, int n_in,
                              void* d_out, int out_size, void* d_ws, size_t ws_size,
                              hipStream_t stream){
  const float* x      = (const float*)d_in[0];
  const float* pos    = (const float*)d_in[1];
  const float* w_norm = (const float*)d_in[2];
  const float* w_in   = (const float*)d_in[3];
  const float* b_in   = (const float*)d_in[4];
  const float* w_out  = (const float*)d_in[5];
  const float* b_out  = (const float*)d_in[6];
  const float* bp     = (const float*)d_in[7];

  char* ws = (char*)d_ws;
  unsigned short* xn    = (unsigned short*)(ws);              // 12,582,912
  unsigned short* winb  = (unsigned short*)(ws + 12582912);   //  3,538,944
  unsigned short* woutb = (unsigned short*)(ws + 16121856);   //  1,179,648
  unsigned short* qpb   = (unsigned short*)(ws + 17301504);   // 12,582,912
  unsigned short* kpb   = (unsigned short*)(ws + 29884416);   // 12,582,912
  unsigned short* vt2b  = (unsigned short*)(ws + 55050240);   // 12,582,912
  float*          table = (float*)        (ws + 67633152);    //    190,512
  unsigned short* ob    = (unsigned short*)(ws + 67823664);   // 12,582,912
  // bmax (48KB) reuses the xn region: written AFTER the QKV GEMM (xn's last reader)
  float*          bmaxp = (float*)        (ws);

  prep_norm_kernel<<<dim3(8192 + 2491), dim3(256), 0, stream>>>(
      x, w_norm, xn, w_in, winb, w_out, woutb, bp, table);
  gemm_bt_kernel<1, 128, unsigned short><<<dim3(64, 18), dim3(256), 0, stream>>>(
      xn, winb, b_in, (unsigned short*)nullptr, qpb, kpb, vt2b, BB*LL, 3*DD, DD);
  bmax_kernel<<<dim3(32, HH), dim3(64), 0, stream>>>(table, bmaxp);
  attn_kernel<<<dim3(1536), dim3(128), 0, stream>>>(qpb, kpb, vt2b, table, bmaxp, pos, ob);
  gemm_bt_kernel<0, 64, float><<<dim3(64, 12), dim3(256), 0, stream>>>(
      ob, woutb, b_out, (float*)d_out, nullptr, nullptr, nullptr, BB*LL, DD, DD);
}

// Round 11
// 210.996 us; speedup vs baseline: 1.0417x; 1.0417x over previous
//
#include <hip/hip_runtime.h>

#define BB 8
#define LL 1024
#define DD 768
#define HH 12
#define HD 64

typedef short s16x8 __attribute__((ext_vector_type(8)));
typedef float f32x4 __attribute__((ext_vector_type(4)));
typedef unsigned int u32x4 __attribute__((ext_vector_type(4)));

static __device__ __forceinline__ unsigned short f2bf(float f){
  unsigned int u = __builtin_bit_cast(unsigned int, f);
  u = (u + 0x7FFFu + ((u >> 16) & 1u)) >> 16;
  return (unsigned short)u;
}

// packed f32x2 -> bf16x2 via hardware cvt_pk (1 VALU); low 16 = a
static __device__ __forceinline__ unsigned int cvtpk_bf(float a, float b){
  unsigned int r;
  asm("v_cvt_pk_bf16_f32 %0, %1, %2" : "=v"(r) : "v"(a), "v"(b));
  return r;
}

// cross-lane swaps (gfx950): swap32: a[32:63] <-> b[0:31];
// swap16 (per 32-lane half): a[16:31] <-> b[0:15], a[48:63] <-> b[32:47]
static __device__ __forceinline__ void swap32(unsigned int& a, unsigned int& b){
  asm("v_permlane32_swap_b32 %0, %1" : "+v"(a), "+v"(b));
}
static __device__ __forceinline__ void swap16(unsigned int& a, unsigned int& b){
  asm("v_permlane16_swap_b32 %0, %1" : "+v"(a), "+v"(b));
}

// hardware exp2: 1 instr, no OCML denormal fixup (inputs <= ~0 here; FTZ ok)
static __device__ __forceinline__ float hexp2(float x){
#if __has_builtin(__builtin_amdgcn_exp2f)
  return __builtin_amdgcn_exp2f(x);
#else
  return exp2f(x);
#endif
}

static __device__ __forceinline__ f32x4 mfma16(s16x8 a, s16x8 b, f32x4 c){
  return __builtin_amdgcn_mfma_f32_16x16x32_bf16(a, b, c, 0, 0, 0);
}

// async global->LDS, 16B per lane; LDS dest is wave-uniform base + lane*16
static __device__ __forceinline__ void gld_lds16(const void* g, void* l){
  __builtin_amdgcn_global_load_lds(
      (const __attribute__((address_space(1))) void*)g,
      (__attribute__((address_space(3))) void*)l, 16, 0, 0);
}

// ------------- merged prep+rmsnorm: one launch (R8, proven) -----------------
__global__ __launch_bounds__(256) void prep_norm_kernel(const float* __restrict__ x,
                                                        const float* __restrict__ wn,
                                                        unsigned short* __restrict__ xn,
                                                        const float* __restrict__ w_in,
                                                        unsigned short* __restrict__ winb,
                                                        const float* __restrict__ w_out,
                                                        unsigned short* __restrict__ woutb,
                                                        const float* __restrict__ bp,
                                                        float* __restrict__ table){
  __shared__ float red[4];
  int bid = blockIdx.x, t = threadIdx.x;
  if (bid < 8192){                                  // ---- RMSNorm -> bf16 ----
    int row = bid;
    const float* xr = x + (size_t)row*DD;
    float v0 = xr[t], v1 = xr[t+256], v2 = xr[t+512];
    float ss = v0*v0 + v1*v1 + v2*v2;
    #pragma unroll
    for (int m = 1; m < 64; m <<= 1) ss += __shfl_xor(ss, m, 64);
    if ((t & 63) == 0) red[t >> 6] = ss;
    __syncthreads();
    float tot = red[0] + red[1] + red[2] + red[3];
    float sc = rsqrtf(tot*(1.0f/DD) + 1e-5f);
    unsigned short* xo = xn + (size_t)row*DD;
    xo[t]     = f2bf(v0*sc*wn[t]);
    xo[t+256] = f2bf(v1*sc*wn[t+256]);
    xo[t+512] = f2bf(v2*sc*wn[t+512]);
  } else if (bid < 8192 + 1728){                    // ---- w_in cvt ----
    int i = (bid - 8192)*256 + t;
    float4 v = ((const float4*)w_in)[i];
    ushort4 o;
    o.x = f2bf(v.x); o.y = f2bf(v.y); o.z = f2bf(v.z); o.w = f2bf(v.w);
    ((ushort4*)winb)[i] = o;
  } else if (bid < 8192 + 2304){                    // ---- w_out cvt ----
    int i = (bid - 8192 - 1728)*256 + t;
    float4 v = ((const float4*)w_out)[i];
    ushort4 o;
    o.x = f2bf(v.x); o.y = f2bf(v.y); o.z = f2bf(v.z); o.w = f2bf(v.w);
    ((ushort4*)woutb)[i] = o;
  } else {                                          // ---- bias table ----
    int idx = (bid - 8192 - 2304)*256 + t;
    if (idx >= HH*3969) return;
    int hh = idx/3969, rem = idx - hh*3969;
    int dy = rem/63 - 31, dx = rem%63 - 31;
    float o  = bp[hh*6+0], c = bp[hh*6+1], w = bp[hh*6+2];
    float p  = bp[hh*6+3], dl = bp[hh*6+4], m = bp[hh*6+5];
    float theta = atan2f((float)dx, (float)dy);     // arctan2(dist1, dist0)
    float r = sqrtf((float)(dy*dy + dx*dx) + 1e-12f);
    float t1 = powf(fmaxf(r - o, 0.0f), fabsf(c));
    float co = cosf((theta - p)*w*0.5f);
    float t2 = 1.0f - fabsf(tanhf(dl))*powf(co*co, fabsf(m));
    table[idx] = t1*t2*1.44269504f;                 // * log2(e)
  }
}

// ---------------- GEMM, 3-stage pipeline, counted vmcnt, LDS chunk-swizzle --------
// C[M,N] = A[M,K] @ B[N,K]^T + bias[N].  Tile 128 x TN, 4 waves 2x2.
// R11: MODE 1 launches 1-D with 1536 blocks; blocks >= 1152 run the bmax
// window-max (table -> bmx) and retire in the GEMM tail, removing one launch.
// bmx lives in its own workspace region (former vpb slot) -> no race with
// xn reads, no ordering assumption between co-dispatched blocks (G16).
template<int MODE, int TN, typename OutT>
__global__ __launch_bounds__(256) void gemm_bt_kernel(const unsigned short* __restrict__ A,
                                                      const unsigned short* __restrict__ B,
                                                      const float* __restrict__ bias,
                                                      OutT* __restrict__ C,
                                                      unsigned short* __restrict__ qp,
                                                      unsigned short* __restrict__ kp,
                                                      unsigned short* __restrict__ vt2,
                                                      const float* __restrict__ tablep,
                                                      float* __restrict__ bmx,
                                                      int M, int N, int K){
  constexpr int NT = TN/32;                 // nt tiles per wave (TN=128 -> 4, TN=64 -> 2)
  constexpr int SMEM_BYTES = 192*(128 + TN);  // 3 A-buffers + 3 B-buffers
  __shared__ __align__(16) char smem[SMEM_BYTES];
  int tid = threadIdx.x;

  if (MODE == 1 && (int)blockIdx.x >= 1152){
    // ---- bmax tail blocks: bmax[h][qy][qx] = max over 32x32 table window ----
    float* m1 = (float*)smem;
    int idx = blockIdx.x - 1152;            // [0, 384) = 12 h x 32 qy
    int qy = idx & 31, h = idx >> 5;
    const float* tb = tablep + h*3969;
    if (tid < 63){
      float m = -3.0e38f;
      #pragma unroll 4
      for (int row = qy; row < qy + 32; row++) m = fmaxf(m, tb[row*63 + tid]);
      m1[tid] = m;
    }
    __syncthreads();
    if (tid < 32){
      float m = -3.0e38f;
      #pragma unroll 4
      for (int c = tid; c < tid + 32; c++) m = fmaxf(m, m1[c]);
      bmx[(h*32 + qy)*32 + tid] = m;
    }
    return;
  }

  unsigned short* As = (unsigned short*)smem;                  // [3][4096]
  unsigned short* Bs = (unsigned short*)(smem + 3*128*32*2);   // [3][TN*32]
  int w = tid >> 6, lane = tid & 63, quad = lane >> 4, col = lane & 15;
  int wm = (w >> 1)*64, wn = (w & 1)*(TN/2);
  int bx, by;
  if (MODE == 1){ bx = blockIdx.x & 63; by = blockIdx.x >> 6; }
  else          { bx = blockIdx.x;      by = blockIdx.y; }
  int bm = bx*128, bn = by*TN;

  int srow = lane >> 2;
  int schunk = (((lane & 3) ^ ((lane >> 3) & 3)))*8;   // swizzled source chunk
  const unsigned short* ga0 = A + (size_t)(bm + w*32 + srow)*K + schunk;
  const unsigned short* ga1 = ga0 + (size_t)16*K;
  const unsigned short* gb0 = B + (size_t)(bn + w*(TN/4) + srow)*K + schunk;
  const unsigned short* gb1 = gb0 + (size_t)16*K;     // only used when TN==128

  auto stage = [&](int t, int bi){
    int kk = t*32;
    gld_lds16(ga0 + kk, As + bi*4096 + (w*32)*32);
    gld_lds16(ga1 + kk, As + bi*4096 + (w*32 + 16)*32);
    gld_lds16(gb0 + kk, Bs + bi*(TN*32) + (w*(TN/4))*32);
    if (TN == 128) gld_lds16(gb1 + kk, Bs + bi*(TN*32) + (w*32 + 16)*32);
  };

  f32x4 acc[4][NT];
  #pragma unroll
  for (int mt = 0; mt < 4; mt++)
    #pragma unroll
    for (int nt = 0; nt < NT; nt++) acc[mt][nt] = (f32x4){0.f,0.f,0.f,0.f};

  // prologue: stage tiles 0 and 1 (2-deep in flight)
  stage(0, 0);
  stage(1, 1);

  int rsw = (col >> 1) & 3;                 // swizzled read chunk = quad ^ rsw
  int rchunk = (quad ^ rsw)*8;

  int KT = K >> 5;
  int buf = 0, nbuf = 2;
  for (int t = 0; t < KT; t++){
    // counted wait BEFORE barrier: own L(t) landed (FIFO vmcnt), newer L(t+1)
    // loads may remain in flight. Barrier then publishes all waves' L(t).
    if (t < KT - 1){
      if (TN == 128) asm volatile("s_waitcnt vmcnt(4)" ::: "memory");
      else           asm volatile("s_waitcnt vmcnt(3)" ::: "memory");
    } else {
      asm volatile("s_waitcnt vmcnt(0)" ::: "memory");
    }
    __builtin_amdgcn_s_barrier();
    asm volatile("" ::: "memory");          // pin LDS reads below the barrier
    if (t + 2 < KT) stage(t + 2, nbuf);
    s16x8 af[4], bfr[NT];
    #pragma unroll
    for (int mt = 0; mt < 4; mt++)
      af[mt] = *(const s16x8*)&As[buf*4096 + (wm + mt*16 + col)*32 + rchunk];
    #pragma unroll
    for (int nt = 0; nt < NT; nt++)
      bfr[nt] = *(const s16x8*)&Bs[buf*(TN*32) + (wn + nt*16 + col)*32 + rchunk];
    #pragma unroll
    for (int mt = 0; mt < 4; mt++)
      #pragma unroll
      for (int nt = 0; nt < NT; nt++)
        acc[mt][nt] = mfma16(af[mt], bfr[nt], acc[mt][nt]);
    buf  = (buf  == 2) ? 0 : buf  + 1;
    nbuf = (nbuf == 2) ? 0 : nbuf + 1;
  }

  if (MODE == 1){
    __syncthreads();                       // all waves done reading As/Bs
    unsigned short* Ct = (unsigned short*)smem;
    if (bn >= 1536){
      // ---- V blocks: fill TRANSPOSED (Ct[col][row]), store in vt2 layout ----
      #pragma unroll
      for (int mt = 0; mt < 4; mt++)
        #pragma unroll
        for (int nt = 0; nt < NT; nt++){
          int cc = wn + nt*16 + col;
          float bv = bias[bn + cc];
          #pragma unroll
          for (int r = 0; r < 4; r++){
            int row = wm + mt*16 + quad*4 + r;
            Ct[cc*136 + row] = f2bf(acc[mt][nt][r] + bv);
          }
        }
      __syncthreads();
      int bb = bm >> 10;
      #pragma unroll
      for (int e = 0; e < 8; e++){
        int id = e*256 + tid;              // 2048 chunks = 128 d-cols x 16 row-chunks
        int dcol = id >> 4, rowch = id & 15;
        s16x8 val = *(const s16x8*)&Ct[dcol*136 + rowch*8];
        int cl = bn + dcol - 1536;
        int h = cl >> 6, d = cl & 63;
        int l = bm + rowch*8;
        size_t base = ((size_t)(bb*HH + h))*65536 + (size_t)((l >> 5) & 31)*2048;
        *(s16x8*)(vt2 + base + d*32 + (l & 31)) = val;
      }
    } else {
      // ---- Q/K blocks: row-major staging, 16B coalesced stores (proven) ----
      #pragma unroll
      for (int mt = 0; mt < 4; mt++)
        #pragma unroll
        for (int nt = 0; nt < NT; nt++){
          int cc = wn + nt*16 + col;
          float bv = bias[bn + cc];
          #pragma unroll
          for (int r = 0; r < 4; r++){
            int row = wm + mt*16 + quad*4 + r;
            Ct[row*136 + cc] = f2bf(acc[mt][nt][r] + bv);
          }
        }
      __syncthreads();
      #pragma unroll
      for (int e = 0; e < 8; e++){
        int id = e*256 + tid;              // 2048 chunks = 128 rows x 16 chunks
        int row = id >> 4, ch = id & 15;
        s16x8 val = *(const s16x8*)&Ct[row*136 + ch*8];
        int rw = bm + row;
        int cl0 = bn + ch*8;
        int part = cl0 >= 768 ? 1 : 0;
        int hd = cl0 - part*768;
        int hh2 = hd >> 6, d0 = hd & 63;
        int bb = rw >> 10, l = rw & 1023;
        size_t base = (((size_t)bb*HH + hh2)*LL + l)*64;
        if (part == 0) *(s16x8*)(qp + base + d0) = val;
        else           *(s16x8*)(kp + base + (((d0>>3) ^ (l&7)) << 3)) = val;
      }
    }
  } else {
    // ---- LDS-staged coalesced f32 epilogue (float4 stores), proven R7 ----
    __syncthreads();
    float* Cf = (float*)smem;              // [128][68] f32, rows 16B-aligned (272B)
    #pragma unroll
    for (int mt = 0; mt < 4; mt++)
      #pragma unroll
      for (int nt = 0; nt < NT; nt++){
        int cc = wn + nt*16 + col;
        float bv = bias[bn + cc];
        #pragma unroll
        for (int r = 0; r < 4; r++){
          int row = wm + mt*16 + quad*4 + r;
          Cf[row*68 + cc] = acc[mt][nt][r] + bv;
        }
      }
    __syncthreads();
    #pragma unroll
    for (int e = 0; e < 8; e++){
      int id = e*256 + tid;                // 2048 chunks = 128 rows x 16 float4
      int row = id >> 4, ch = id & 15;
      float4 val = *(const float4*)&Cf[row*68 + ch*4];
      *(float4*)&C[(size_t)(bm + row)*N + bn + ch*4] = val;
    }
  }
}

// ---------------- fused attention: barrier-free, 4-wave blocks (R3, 56.0us) ----
// R11: reverted to the fastest measured attn form — grid 768 x 256 threads,
// 32 q-rows/wave with the g-loop. The 2-wave split (R6) was 57.3 (slower),
// K-split (R8) 65.8, setprio (R7) and chain-fold (R10) both negative.
__global__ __launch_bounds__(256) void attn_kernel(const unsigned short* __restrict__ qp,
                                                   const unsigned short* __restrict__ kp,
                                                   const unsigned short* __restrict__ vt2,
                                                   const float* __restrict__ table,
                                                   const float* __restrict__ bmax,
                                                   const float* __restrict__ pos,
                                                   unsigned short* __restrict__ o_out){
  int i = blockIdx.x;
  int bh = (i >> 6)*8 + (i & 7);          // i%8 == bh%8 (XCD-local K/V)
  int qt = (i >> 3) & 7;
  int b = bh/HH, h = bh - b*HH;
  int tid = threadIdx.x, w = tid >> 6, lane = tid & 63, quad = lane >> 4, col = lane & 15;
  __shared__ float tl[3969];

  const unsigned short* kgp = kp  + (size_t)bh*65536;
  const unsigned short* vgp = vt2 + (size_t)bh*65536;

  // per-lane fragment offsets (in shorts):
  // K: row=key=col (stride 64), chunk c at position c^(col&7) (GEMM swizzle)
  // V: row=d=col (stride 32), j-chunk = quad
  int sw = col & 7;
  int k_r0 = col*64 + ((quad ^ sw) << 3);          // keys 0-15,  d = quad*8
  int k_r1 = col*64 + (((quad + 4) ^ sw) << 3);    // keys 0-15,  d = 32+quad*8
  int v_r  = col*32 + quad*8;                      // d = col,    j = quad*8

  s16x8 kA[4], vA[4], kB[4], vB[4];
  auto issue = [&](int t, s16x8 (&k)[4], s16x8 (&v)[4]){
    const unsigned short* kt = kgp + t*2048;
    const unsigned short* vt = vgp + t*2048;
    k[0] = *(const s16x8*)(kt + k_r0);
    k[1] = *(const s16x8*)(kt + k_r1);
    k[2] = *(const s16x8*)(kt + 1024 + k_r0);      // keys 16-31
    k[3] = *(const s16x8*)(kt + 1024 + k_r1);
    v[0] = *(const s16x8*)(vt + v_r);
    v[1] = *(const s16x8*)(vt + v_r + 512);
    v[2] = *(const s16x8*)(vt + v_r + 1024);
    v[3] = *(const s16x8*)(vt + v_r + 1536);
  };
  issue(0, kA, vA);                 // overlap with tl staging
  issue(1, kB, vB);

  for (int j = tid; j < 3969; j += 256) tl[j] = table[h*3969 + j];
  const float* pb = pos + (size_t)b*2048;

  int qw = qt*128 + w*32;
  const unsigned short* qpb = qp + (size_t)bh*65536;
  s16x8 qa[2][2];
  int cq[2];
  f32x4 zb[2];                              // QK acc init = -mh/scale (folds max-sub)
  #pragma unroll
  for (int g = 0; g < 2; g++){
    int q = qw + g*16 + col;
    size_t qo = (size_t)q*64 + quad*8;
    qa[g][0] = *(const s16x8*)(qpb + qo);
    qa[g][1] = *(const s16x8*)(qpb + qo + 32);
    int qy = __float2int_rn(pb[q*2]);
    int qx = __float2int_rn(pb[q*2 + 1]);
    cq[g] = qy*63 + qx + 1984 - quad*4;
    float neg = -5.5451774445f * bmax[(h*32 + qy)*32 + qx];   // -mh / 0.18033688
    zb[g] = (f32x4){neg, neg, neg, neg};
  }

  s16x8 ones;                               // bf16 1.0 row for the l-sum MFMA
  #pragma unroll
  for (int e = 0; e < 8; e++) ones[e] = (short)0x3F80;

  f32x4 o[2][4];
  f32x4 l_acc[2];
  #pragma unroll
  for (int g = 0; g < 2; g++){
    #pragma unroll
    for (int nt = 0; nt < 4; nt++) o[g][nt] = (f32x4){0.f,0.f,0.f,0.f};
    l_acc[g] = (f32x4){0.f,0.f,0.f,0.f};
  }

  __syncthreads();                          // tl visible (only barrier in kernel)

  auto step = [&](int t, s16x8 (&k)[4], s16x8 (&v)[4]){
    int kyt = 63*t;                         // pos grid is raster: ky63[t]=63t
    #pragma unroll
    for (int g = 0; g < 2; g++){
      f32x4 s_lo = mfma16(k[0], qa[g][0], zb[g]);  s_lo = mfma16(k[1], qa[g][1], s_lo);
      f32x4 s_hi = mfma16(k[2], qa[g][0], zb[g]);  s_hi = mfma16(k[3], qa[g][1], s_hi);
      int base = cq[g] - kyt;
      float pl[4], ph[4];
      #pragma unroll
      for (int r = 0; r < 4; r++){
        pl[r] = hexp2(__builtin_fmaf(s_lo[r], 0.18033688f, tl[base - r]));
        ph[r] = hexp2(__builtin_fmaf(s_hi[r], 0.18033688f, tl[base - r - 16]));
      }
      // lane holds P for keys {4q..4q+3} (pl) and {16+4q..16+4q+3} (ph), q=quad.
      // cvt_pk + 4 permlane swaps deliver the PV B-fragment to every quad.
      unsigned int wA = cvtpk_bf(pl[0], pl[1]);
      unsigned int wB = cvtpk_bf(pl[2], pl[3]);
      unsigned int wC = cvtpk_bf(ph[0], ph[1]);
      unsigned int wD = cvtpk_bf(ph[2], ph[3]);
      swap32(wA, wC);  swap32(wB, wD);
      swap16(wA, wC);  swap16(wB, wD);
      u32x4 pv4; pv4.x = wA; pv4.y = wB; pv4.z = wC; pv4.w = wD;
      s16x8 pf = __builtin_bit_cast(s16x8, pv4);
      l_acc[g] = mfma16(ones, pf, l_acc[g]);    // denominator on the MFMA pipe
      o[g][0] = mfma16(v[0], pf, o[g][0]);
      o[g][1] = mfma16(v[1], pf, o[g][1]);
      o[g][2] = mfma16(v[2], pf, o[g][2]);
      o[g][3] = mfma16(v[3], pf, o[g][3]);
    }
  };

  for (int t = 0; t < 32; t += 2){
    step(t, kA, vA);
    if (t + 2 < 32) issue(t + 2, kA, vA);   // reissue after last use (WAR ok)
    step(t + 1, kB, vB);
    if (t + 3 < 32) issue(t + 3, kB, vB);
  }

  #pragma unroll
  for (int g = 0; g < 2; g++){
    float inv = 1.0f / l_acc[g][0];           // full sum already in every lane
    int q = qw + g*16 + col;
    unsigned short* orow = o_out + (size_t)(b*LL + q)*DD + h*64;
    #pragma unroll
    for (int nt = 0; nt < 4; nt++){
      uint2 pkd;
      pkd.x = cvtpk_bf(o[g][nt][0]*inv, o[g][nt][1]*inv);
      pkd.y = cvtpk_bf(o[g][nt][2]*inv, o[g][nt][3]*inv);
      *(uint2*)&orow[nt*16 + quad*4] = pkd;
    }
  }
}

extern "C" void kernel_launch(void* const* d_in, const int* in_sizes, int n_in,
                              void* d_out, int out_size, void* d_ws, size_t ws_size,
                              hipStream_t stream){
  const float* x      = (const float*)d_in[0];
  const float* pos    = (const float*)d_in[1];
  const float* w_norm = (const float*)d_in[2];
  const float* w_in   = (const float*)d_in[3];
  const float* b_in   = (const float*)d_in[4];
  const float* w_out  = (const float*)d_in[5];
  const float* b_out  = (const float*)d_in[6];
  const float* bp     = (const float*)d_in[7];

  char* ws = (char*)d_ws;
  unsigned short* xn    = (unsigned short*)(ws);              // 12,582,912
  unsigned short* winb  = (unsigned short*)(ws + 12582912);   //  3,538,944
  unsigned short* woutb = (unsigned short*)(ws + 16121856);   //  1,179,648
  unsigned short* qpb   = (unsigned short*)(ws + 17301504);   // 12,582,912
  unsigned short* kpb   = (unsigned short*)(ws + 29884416);   // 12,582,912
  float*          bmaxp = (float*)        (ws + 42467328);    // 49,152 (own region:
                                                              // NO xn alias — bmax now
                                                              // co-dispatched with GEMM)
  unsigned short* vt2b  = (unsigned short*)(ws + 55050240);   // 12,582,912
  float*          table = (float*)        (ws + 67633152);    //    190,512
  unsigned short* ob    = (unsigned short*)(ws + 67823664);   // 12,582,912

  prep_norm_kernel<<<dim3(8192 + 2491), dim3(256), 0, stream>>>(
      x, w_norm, xn, w_in, winb, w_out, woutb, bp, table);
  // QKV GEMM (1152 blocks) + bmax tail (384 blocks) in one dispatch
  gemm_bt_kernel<1, 128, unsigned short><<<dim3(1536), dim3(256), 0, stream>>>(
      xn, winb, b_in, (unsigned short*)nullptr, qpb, kpb, vt2b, table, bmaxp,
      BB*LL, 3*DD, DD);
  attn_kernel<<<dim3(768), dim3(256), 0, stream>>>(qpb, kpb, vt2b, table, bmaxp, pos, ob);
  gemm_bt_kernel<0, 64, float><<<dim3(64, 12), dim3(256), 0, stream>>>(
      ob, woutb, b_out, (float*)d_out, nullptr, nullptr, nullptr, nullptr, nullptr,
      BB*LL, DD, DD);
}